// Round 7
// baseline (264.250 us; speedup 1.0000x reference)
//
#include <hip/hip_runtime.h>

#define B_ 8
#define T_ 4096
#define D_ 768
#define NH_ 12
#define M_ 64
#define ALPHA_ 0.1f

#define CCH 16         // chunks over T
#define CHUNK_T 256    // t per block

using half8 = __attribute__((ext_vector_type(8))) _Float16;
using short8 = __attribute__((ext_vector_type(8))) short;
using f32x4 = __attribute__((ext_vector_type(4))) float;

__device__ __forceinline__ unsigned int f2h2(float a, float b) {
    unsigned short ua = __builtin_bit_cast(unsigned short, (_Float16)a);
    unsigned short ub = __builtin_bit_cast(unsigned short, (_Float16)b);
    return (unsigned int)ua | ((unsigned int)ub << 16);
}
__device__ __forceinline__ float h2f(unsigned short u) {
    return (float)__builtin_bit_cast(_Float16, u);
}
// async global->LDS, 16 B per lane; LDS dst must be wave-uniform base + lane*16
__device__ __forceinline__ void gload_lds16(const void* g, void* l) {
    __builtin_amdgcn_global_load_lds(
        (const __attribute__((address_space(1))) unsigned int*)g,
        (__attribute__((address_space(3))) unsigned int*)l, 16, 0, 0);
}
// LDS-only barrier: waits ds ops, does NOT drain vmcnt -> global prefetches
// (av register loads) stay in flight across it. T4/T18 pattern.
__device__ __forceinline__ void barrier_lgkm() {
    asm volatile("s_waitcnt lgkmcnt(0)" ::: "memory");
    __builtin_amdgcn_s_barrier();
}

// ---------------------------------------------------------------------------
// Kernel kP: P[h,m,e] = (1/8) * sum_i proto[m, h*64+i] * W[h*64+i, e] -> fp16.
// ---------------------------------------------------------------------------
__global__ __launch_bounds__(256) void kP(const float* __restrict__ proto,
                                          const float* __restrict__ W,
                                          unsigned short* __restrict__ P16) {
    const int et = blockIdx.x;
    const int h  = blockIdx.y;
    const int tid = threadIdx.x;

    __shared__ __align__(16) float Ws[64 * 128];
    __shared__ __align__(16) float Ks[64 * 64];

#pragma unroll
    for (int j = 0; j < 8; ++j) {
        int f = tid + j * 256;
        int i = f >> 5, c4 = f & 31;
        const float4 v = *reinterpret_cast<const float4*>(
            W + (size_t)(h * 64 + i) * D_ + et * 128 + c4 * 4);
        *reinterpret_cast<float4*>(&Ws[i * 128 + c4 * 4]) = v;
    }
#pragma unroll
    for (int j = 0; j < 4; ++j) {
        int f = tid + j * 256;
        int m = f >> 4, i4 = f & 15;
        const float4 v = *reinterpret_cast<const float4*>(
            proto + (size_t)m * D_ + h * 64 + i4 * 4);
        Ks[(i4 * 4 + 0) * 64 + m] = v.x;
        Ks[(i4 * 4 + 1) * 64 + m] = v.y;
        Ks[(i4 * 4 + 2) * 64 + m] = v.z;
        Ks[(i4 * 4 + 3) * 64 + m] = v.w;
    }
    __syncthreads();

    const int m0 = (tid >> 5) * 8;
    const int e0 = (tid & 31) * 4;
    float acc[8][4];
#pragma unroll
    for (int i = 0; i < 8; ++i)
#pragma unroll
        for (int j = 0; j < 4; ++j) acc[i][j] = 0.f;

    for (int i = 0; i < 64; ++i) {
        const float4 bb = *reinterpret_cast<const float4*>(&Ws[i * 128 + e0]);
        const float4 a0 = *reinterpret_cast<const float4*>(&Ks[i * 64 + m0]);
        const float4 a1 = *reinterpret_cast<const float4*>(&Ks[i * 64 + m0 + 4]);
        const float a[8] = {a0.x, a0.y, a0.z, a0.w, a1.x, a1.y, a1.z, a1.w};
#pragma unroll
        for (int mi = 0; mi < 8; ++mi) {
            acc[mi][0] = fmaf(a[mi], bb.x, acc[mi][0]);
            acc[mi][1] = fmaf(a[mi], bb.y, acc[mi][1]);
            acc[mi][2] = fmaf(a[mi], bb.z, acc[mi][2]);
            acc[mi][3] = fmaf(a[mi], bb.w, acc[mi][3]);
        }
    }
#pragma unroll
    for (int mi = 0; mi < 8; ++mi) {
        size_t idx = (size_t)(h * 64 + m0 + mi) * D_ + et * 128 + e0;
        uint2 pk = {f2h2(acc[mi][0] * 0.125f, acc[mi][1] * 0.125f),
                    f2h2(acc[mi][2] * 0.125f, acc[mi][3] * 0.125f)};
        *reinterpret_cast<uint2*>(P16 + idx) = pk;
    }
}

// ---------------------------------------------------------------------------
// Kernel 1: per (chunk=256t, head-PAIR, batch). 512 threads / 8 waves.
// Reads H fp32 directly (no H16 pass). A-staging = register prefetch:
// LOADA(kt+1) issued after barrier2 + sched_barrier pin; barrier1 is
// lgkm-ONLY (r6's __syncthreads there drained vmcnt(0) -> killed the
// prefetch every iter, k1 113us). WRITEA converts fp32->fp16 into the
// proven r1 XOR-granule LDS layout; B (P16) stays on the DMA path.
// grid 768 (b = p&7 pins batch per XCD), dyn LDS 69632 B, 2 blocks/CU.
//
// LDS (bytes): [0,32768) A f16[256t][64k] swz | [32768,49152) B f16[2h][64m][64k]
//   alias: [0,33792) wT f16[64m][264t] | [33792,67584) Hh f16[64d][264t]
//   [67584,69632) segprod f32[8][64]
// ---------------------------------------------------------------------------
#define LDS_BYTES 69632

// slot sl = j*512+tid -> row r = j*64 + (tid>>3), granule g = (tid&7) ^ (r&7)
#define LOADA(KT) do {                                                         \
    _Pragma("unroll")                                                          \
    for (int j_ = 0; j_ < 4; ++j_) {                                           \
        const float* p_ = gAf + (size_t)(ar + j_ * 64) * D_ + (KT) * 64 + ag * 8; \
        av0[j_] = *reinterpret_cast<const float4*>(p_);                        \
        av1[j_] = *reinterpret_cast<const float4*>(p_ + 4);                    \
    }                                                                          \
} while (0)

#define WRITEA() do {                                                          \
    _Pragma("unroll")                                                          \
    for (int j_ = 0; j_ < 4; ++j_) {                                           \
        uint4 w_;                                                              \
        w_.x = f2h2(av0[j_].x, av0[j_].y);                                     \
        w_.y = f2h2(av0[j_].z, av0[j_].w);                                     \
        w_.z = f2h2(av1[j_].x, av1[j_].y);                                     \
        w_.w = f2h2(av1[j_].z, av1[j_].w);                                     \
        *reinterpret_cast<uint4*>(smem + (j_ * 512 + tid) * 16) = w_;          \
    }                                                                          \
} while (0)

__global__ __launch_bounds__(512, 4) void k1(const float* __restrict__ Hf,
                                             const unsigned short* __restrict__ P16,
                                             float* __restrict__ chunkprod,
                                             float* __restrict__ partial) {
    const int p = blockIdx.x;
    const int b = p & 7;
    const int s = p >> 3;
    const int hp = s % 6;          // head pair index
    const int c  = s / 6;
    const int tid = threadIdx.x;
    const int wv  = tid >> 6;      // 0..7
    const int lane = tid & 63;
    const int l15 = lane & 15;
    const int q4  = lane >> 4;
    const int hl  = wv >> 2;       // wave's head_local (0/1)
    const int tq  = wv & 3;        // wave's t-quarter

    extern __shared__ __align__(16) unsigned char smem[];
    unsigned short* wT = (unsigned short*)(smem);
    unsigned short* Hh = (unsigned short*)(smem + 33792);
    float* segprod = (float*)(smem + 67584);

    const size_t Hrow = (size_t)(b * T_ + c * CHUNK_T);
    const float* gAf = Hf + Hrow * D_;
    const unsigned short* gB = P16 + (size_t)(hp * 2) * 64 * D_;

    // ======== score GEMM: 256t x (2h x 64m), K=768, fp16 ===================
    f32x4 acc[4][4] = {};   // t = tq*64+tt*16+q4*4+rg (row), m = mt*16+l15 (col)

    const int ar = tid >> 3;                 // A slot base row (0..63)
    const int ag = (tid & 7) ^ (ar & 7);     // A data granule (XOR swizzle)
    float4 av0[4], av1[4];                   // A reg prefetch (32 VGPR)

    LOADA(0);
    __builtin_amdgcn_sched_barrier(0);
    for (int kt = 0; kt < 12; ++kt) {
        // barrier1: previous MFMA phase's LDS frag reads done -> A/B LDS
        // writable. lgkm-ONLY: av prefetch loads stay in flight across it.
        barrier_lgkm();
        // B: 1024 granules (2 heads x 512) via DMA
#pragma unroll
        for (int j = 0; j < 2; ++j) {
            int sl = j * 512 + tid;
            int r = (sl & 511) >> 3, gp = sl & 7, g = gp ^ (r & 7);
            gload_lds16(gB + (size_t)(j * 64 + r) * D_ + kt * 64 + g * 8,
                        smem + 32768 + sl * 16);
        }
        WRITEA();           // cvt fp32->fp16 + ds_write (compiler waits av here)
        __syncthreads();    // barrier2: drains B-DMA + A ds_writes
        if (kt < 11) {
            LOADA(kt + 1);  // issue next A prefetch; completes during MFMAs
            __builtin_amdgcn_sched_barrier(0);   // pin: loads can't sink
        }
#pragma unroll
        for (int ks = 0; ks < 2; ++ks) {
            const int gp = ((ks * 4 + q4) ^ (l15 & 7)) * 16;
            half8 af[4], bf[4];
#pragma unroll
            for (int tt = 0; tt < 4; ++tt)
                af[tt] = *reinterpret_cast<const half8*>(
                    smem + (tq * 64 + tt * 16 + l15) * 128 + gp);
#pragma unroll
            for (int mt = 0; mt < 4; ++mt)
                bf[mt] = *reinterpret_cast<const half8*>(
                    smem + 32768 + hl * 8192 + (mt * 16 + l15) * 128 + gp);
#pragma unroll
            for (int tt = 0; tt < 4; ++tt)
#pragma unroll
                for (int mt = 0; mt < 4; ++mt)
                    acc[tt][mt] = __builtin_amdgcn_mfma_f32_16x16x32_f16(
                        af[tt], bf[mt], acc[tt][mt], 0, 0, 0);
        }
    }

    // ======== softmax over m in registers (reduce over l15), no max-sub ====
#pragma unroll
    for (int tt = 0; tt < 4; ++tt)
#pragma unroll
        for (int rg = 0; rg < 4; ++rg) {
            float e0 = __expf(acc[tt][0][rg]);
            float e1 = __expf(acc[tt][1][rg]);
            float e2 = __expf(acc[tt][2][rg]);
            float e3 = __expf(acc[tt][3][rg]);
            float sm = (e0 + e1) + (e2 + e3);
#pragma unroll
            for (int msk = 1; msk <= 8; msk <<= 1)
                sm += __shfl_xor(sm, msk, 64);
            float inv = __builtin_amdgcn_rcpf(sm);
            acc[tt][0][rg] = e0 * inv;
            acc[tt][1][rg] = e1 * inv;
            acc[tt][2][rg] = e2 * inv;
            acc[tt][3][rg] = e3 * inv;
        }
    __syncthreads();   // score-phase frag reads done; wT/Hh alias A/B

    const int m_s = tid & 63;
    const int g8  = tid >> 6;    // segment index (== wv)

    // ======== per-head: pack wT -> suffix scan -> partial GEMM =============
    for (int head = 0; head < 2; ++head) {
        const int h = hp * 2 + head;
        const int chunkIdx = (b * NH_ + h) * CCH + c;

        // pack w -> wT[m][t] fp16, pitch 264 (this head's waves only)
        if (hl == head) {
#pragma unroll
            for (int tt = 0; tt < 4; ++tt)
#pragma unroll
                for (int mt = 0; mt < 4; ++mt) {
                    uint2 pk = {f2h2(acc[tt][mt][0], acc[tt][mt][1]),
                                f2h2(acc[tt][mt][2], acc[tt][mt][3])};
                    *reinterpret_cast<uint2*>(
                        wT + (mt * 16 + l15) * 264 + tq * 64 + tt * 16 + q4 * 4) = pk;
                }
        }
        // stage Hh: H fp32 [256t][64d] head slice -> f16 [d][t], pitch 264
        {
            const int dp = tid & 31, tg = tid >> 5;
            const float* src = Hf + (Hrow + tg * 16) * D_ + h * 64 + 2 * dp;
            unsigned short* dst0 = Hh + (2 * dp) * 264 + tg * 16;
            unsigned short* dst1 = Hh + (2 * dp + 1) * 264 + tg * 16;
#pragma unroll
            for (int i = 0; i < 8; ++i) {
                const float2 a = *reinterpret_cast<const float2*>(
                    src + (size_t)(2 * i) * D_);
                const float2 bb = *reinterpret_cast<const float2*>(
                    src + (size_t)(2 * i + 1) * D_);
                *reinterpret_cast<unsigned int*>(dst0 + 2 * i) = f2h2(a.x, bb.x);
                *reinterpret_cast<unsigned int*>(dst1 + 2 * i) = f2h2(a.y, bb.y);
            }
        }
        __syncthreads();

        // segmented suffix gate scan: 8 segments x 32 t, all 512 threads
        {
            unsigned short* rowp = wT + m_s * 264 + g8 * 32;
            float pband = 1.0f;
#pragma unroll
            for (int oct = 0; oct < 4; ++oct) {
                short8 v = *reinterpret_cast<const short8*>(rowp + oct * 8);
#pragma unroll
                for (int j = 0; j < 8; ++j)
                    pband *= fmaf(-ALPHA_, h2f((unsigned short)v[j]), 1.0f);
            }
            segprod[g8 * 64 + m_s] = pband;
            __syncthreads();
            float R = 1.0f;
#pragma unroll
            for (int gg = 1; gg < 8; ++gg)
                if (g8 + gg < 8) R *= segprod[(g8 + gg) * 64 + m_s];
            if (g8 == 0)
                chunkprod[(size_t)chunkIdx * 64 + m_s] = R * pband;
#pragma unroll
            for (int oct = 3; oct >= 0; --oct) {
                short8 v = *reinterpret_cast<const short8*>(rowp + oct * 8);
                short8 o;
#pragma unroll
                for (int j = 7; j >= 0; --j) {
                    float w = h2f((unsigned short)v[j]);
                    _Float16 we = (_Float16)(ALPHA_ * w * R);
                    o[j] = (short)__builtin_bit_cast(unsigned short, we);
                    R *= fmaf(-ALPHA_, w, 1.0f);
                }
                *reinterpret_cast<short8*>(rowp + oct * 8) = o;
            }
        }
        __syncthreads();   // w_eff + Hh visible

        // partial GEMM: pacc[m][d] += w_eff^T . H_head; wave = (mt=w&3, dh=w>>2)
        {
            const int mt = wv & 3;
            const int dh = wv >> 2;
            f32x4 pacc[2] = {};
#pragma unroll
            for (int ks = 0; ks < 8; ++ks) {
                half8 a = *reinterpret_cast<const half8*>(
                    wT + (mt * 16 + l15) * 264 + ks * 32 + q4 * 8);
#pragma unroll
                for (int dt = 0; dt < 2; ++dt) {
                    half8 bb = *reinterpret_cast<const half8*>(
                        Hh + (dh * 32 + dt * 16 + l15) * 264 + ks * 32 + q4 * 8);
                    pacc[dt] = __builtin_amdgcn_mfma_f32_16x16x32_f16(
                        a, bb, pacc[dt], 0, 0, 0);
                }
            }
#pragma unroll
            for (int dt = 0; dt < 2; ++dt)
#pragma unroll
                for (int rg = 0; rg < 4; ++rg)
                    partial[((size_t)chunkIdx * 64 + mt * 16 + q4 * 4 + rg) * 64
                            + dh * 32 + dt * 16 + l15] = pacc[dt][rg];
        }
        if (head == 0) __syncthreads();   // wT/Hh reuse for head 1
    }
}

// ---------------------------------------------------------------------------
// Kernel 2: combine 16 chunks; grid (12, 8, 4) — mg picks 16 m-rows.
// ---------------------------------------------------------------------------
__global__ __launch_bounds__(256) void k2(const float* __restrict__ chunkprod,
                                          const float* __restrict__ partial,
                                          const float* __restrict__ s0,
                                          float* __restrict__ out) {
    const int h = blockIdx.x;
    const int b = blockIdx.y;
    const int mg = blockIdx.z;
    const int tid = threadIdx.x;
    const int m  = mg * 16 + (tid >> 4);
    const int d0 = (tid & 15) * 4;

    const size_t cpBase = (size_t)(b * NH_ + h) * CCH;
    float sfx[CCH];
    float run = 1.0f;
#pragma unroll
    for (int c = CCH - 1; c >= 0; --c) {
        sfx[c] = run;
        run *= chunkprod[(cpBase + c) * M_ + m];
    }
    const float4 v0 = *reinterpret_cast<const float4*>(
        s0 + (size_t)m * D_ + h * 64 + d0);
    float4 acc = make_float4(v0.x * run, v0.y * run, v0.z * run, v0.w * run);
#pragma unroll
    for (int c = 0; c < CCH; ++c) {
        const float sv = sfx[c];
        const float4 pp = *reinterpret_cast<const float4*>(
            partial + ((cpBase + c) * M_ + m) * 64 + d0);
        acc.x = fmaf(sv, pp.x, acc.x);
        acc.y = fmaf(sv, pp.y, acc.y);
        acc.z = fmaf(sv, pp.z, acc.z);
        acc.w = fmaf(sv, pp.w, acc.w);
    }
    *reinterpret_cast<float4*>(out + (size_t)(b * M_ + m) * D_ + h * 64 + d0) = acc;
}

// ---------------------------------------------------------------------------
extern "C" void kernel_launch(void* const* d_in, const int* in_sizes, int n_in,
                              void* d_out, int out_size, void* d_ws, size_t ws_size,
                              hipStream_t stream) {
    const float* H     = (const float*)d_in[0];
    const float* proto = (const float*)d_in[1];
    const float* W     = (const float*)d_in[2];
    const float* s0    = (const float*)d_in[3];
    float* out = (float*)d_out;

    // ws: P16 u16[589824] (1.18 MB) | chunkprod f32[98304] (0.39 MB)
    //     | partial f32[6291456] (25.2 MB)   ~26.7 MB total
    unsigned short* P16 = (unsigned short*)d_ws;
    float* chunkprod = (float*)((unsigned char*)d_ws + 1179648);
    float* partial   = (float*)((unsigned char*)d_ws + 1572864);

    kP<<<dim3(6, NH_), 256, 0, stream>>>(proto, W, P16);
    k1<<<dim3(768), 512, LDS_BYTES, stream>>>(H, P16, chunkprod, partial);
    k2<<<dim3(NH_, B_, 4), 256, 0, stream>>>(chunkprod, partial, s0, out);
}

// Round 8
// 233.605 us; speedup vs baseline: 1.1312x; 1.1312x over previous
//
#include <hip/hip_runtime.h>

#define B_ 8
#define T_ 4096
#define D_ 768
#define NH_ 12
#define M_ 64
#define ALPHA_ 0.1f

#define CCH 16         // chunks over T
#define CHUNK_T 256    // t per block

using half8 = __attribute__((ext_vector_type(8))) _Float16;
using short8 = __attribute__((ext_vector_type(8))) short;
using f32x4 = __attribute__((ext_vector_type(4))) float;

__device__ __forceinline__ unsigned int f2h2(float a, float b) {
    unsigned short ua = __builtin_bit_cast(unsigned short, (_Float16)a);
    unsigned short ub = __builtin_bit_cast(unsigned short, (_Float16)b);
    return (unsigned int)ua | ((unsigned int)ub << 16);
}
__device__ __forceinline__ float h2f(unsigned short u) {
    return (float)__builtin_bit_cast(_Float16, u);
}
// async global->LDS, 16 B per lane; LDS dst must be wave-uniform base + lane*16
__device__ __forceinline__ void gload_lds16(const void* g, void* l) {
    __builtin_amdgcn_global_load_lds(
        (const __attribute__((address_space(1))) unsigned int*)g,
        (__attribute__((address_space(3))) unsigned int*)l, 16, 0, 0);
}

// ---------------------------------------------------------------------------
// Kernel kP: P[h,m,e] = (1/8) * sum_i proto[m, h*64+i] * W[h*64+i, e] -> fp16.
// ---------------------------------------------------------------------------
__global__ __launch_bounds__(256) void kP(const float* __restrict__ proto,
                                          const float* __restrict__ W,
                                          unsigned short* __restrict__ P16) {
    const int et = blockIdx.x;
    const int h  = blockIdx.y;
    const int tid = threadIdx.x;

    __shared__ __align__(16) float Ws[64 * 128];
    __shared__ __align__(16) float Ks[64 * 64];

#pragma unroll
    for (int j = 0; j < 8; ++j) {
        int f = tid + j * 256;
        int i = f >> 5, c4 = f & 31;
        const float4 v = *reinterpret_cast<const float4*>(
            W + (size_t)(h * 64 + i) * D_ + et * 128 + c4 * 4);
        *reinterpret_cast<float4*>(&Ws[i * 128 + c4 * 4]) = v;
    }
#pragma unroll
    for (int j = 0; j < 4; ++j) {
        int f = tid + j * 256;
        int m = f >> 4, i4 = f & 15;
        const float4 v = *reinterpret_cast<const float4*>(
            proto + (size_t)m * D_ + h * 64 + i4 * 4);
        Ks[(i4 * 4 + 0) * 64 + m] = v.x;
        Ks[(i4 * 4 + 1) * 64 + m] = v.y;
        Ks[(i4 * 4 + 2) * 64 + m] = v.z;
        Ks[(i4 * 4 + 3) * 64 + m] = v.w;
    }
    __syncthreads();

    const int m0 = (tid >> 5) * 8;
    const int e0 = (tid & 31) * 4;
    float acc[8][4];
#pragma unroll
    for (int i = 0; i < 8; ++i)
#pragma unroll
        for (int j = 0; j < 4; ++j) acc[i][j] = 0.f;

    for (int i = 0; i < 64; ++i) {
        const float4 bb = *reinterpret_cast<const float4*>(&Ws[i * 128 + e0]);
        const float4 a0 = *reinterpret_cast<const float4*>(&Ks[i * 64 + m0]);
        const float4 a1 = *reinterpret_cast<const float4*>(&Ks[i * 64 + m0 + 4]);
        const float a[8] = {a0.x, a0.y, a0.z, a0.w, a1.x, a1.y, a1.z, a1.w};
#pragma unroll
        for (int mi = 0; mi < 8; ++mi) {
            acc[mi][0] = fmaf(a[mi], bb.x, acc[mi][0]);
            acc[mi][1] = fmaf(a[mi], bb.y, acc[mi][1]);
            acc[mi][2] = fmaf(a[mi], bb.z, acc[mi][2]);
            acc[mi][3] = fmaf(a[mi], bb.w, acc[mi][3]);
        }
    }
#pragma unroll
    for (int mi = 0; mi < 8; ++mi) {
        size_t idx = (size_t)(h * 64 + m0 + mi) * D_ + et * 128 + e0;
        uint2 pk = {f2h2(acc[mi][0] * 0.125f, acc[mi][1] * 0.125f),
                    f2h2(acc[mi][2] * 0.125f, acc[mi][3] * 0.125f)};
        *reinterpret_cast<uint2*>(P16 + idx) = pk;
    }
}

// ---------------------------------------------------------------------------
// Kernel 1: per (chunk=256t, head-PAIR, batch). 512 threads / 8 waves; wave w
// owns (head_local = w>>2, t-quarter = w&3). Reads H fp32 DIRECTLY.
// A staged as RAW FP32 via global_load_lds (r1's sync structure: sync ->
// stage-DMA -> sync -> compute; the reg-prefetch variants r6/r7 spilled and
// lost 50-90us). fp32->fp16 conversion happens at frag-read time: two
// ds_read_b128 per frag + 4 f2h2 (each A element converted exactly once).
// B (P16) staging/reads byte-identical to r1. grid 768 (b=p&7 pins XCD),
// dyn LDS 81920 B = 160KB/2 -> still 2 blocks/CU.
//
// LDS (bytes): [0,65536) A f32[256t][64k] 16-granule XOR swz
//              [65536,81920) B f16[2h][64m][64k] 8-granule XOR swz
//   tail alias: [0,33792) wT f16[64m][264t] | [33792,67584) Hh f16[64d][264t]
//   [67584,69632) segprod f32[8][64]
// ---------------------------------------------------------------------------
#define LDS_BYTES 81920

__global__ __launch_bounds__(512, 4) void k1(const float* __restrict__ Hf,
                                             const unsigned short* __restrict__ P16,
                                             float* __restrict__ chunkprod,
                                             float* __restrict__ partial) {
    const int p = blockIdx.x;
    const int b = p & 7;
    const int s = p >> 3;
    const int hp = s % 6;          // head pair index
    const int c  = s / 6;
    const int tid = threadIdx.x;
    const int wv  = tid >> 6;      // 0..7
    const int lane = tid & 63;
    const int l15 = lane & 15;
    const int q4  = lane >> 4;
    const int hl  = wv >> 2;       // wave's head_local (0/1)
    const int tq  = wv & 3;        // wave's t-quarter

    extern __shared__ __align__(16) unsigned char smem[];
    unsigned short* wT = (unsigned short*)(smem);
    unsigned short* Hh = (unsigned short*)(smem + 33792);
    float* segprod = (float*)(smem + 67584);

    const size_t Hrow = (size_t)(b * T_ + c * CHUNK_T);
    const float* gAf = Hf + Hrow * D_;
    const unsigned short* gB = P16 + (size_t)(hp * 2) * 64 * D_;

    // ======== score GEMM: 256t x (2h x 64m), K=768, A fp32-in-LDS ==========
    f32x4 acc[4][4] = {};   // t = tq*64+tt*16+q4*4+rg (row), m = mt*16+l15 (col)

    for (int kt = 0; kt < 12; ++kt) {
        __syncthreads();
        // A: 4096 granules of 16 B (4 floats); slot sl -> row r=sl>>4,
        // lds-granule gp=sl&15, fetched data granule g = gp ^ (r&15)
#pragma unroll
        for (int j = 0; j < 8; ++j) {
            int sl = j * 512 + tid;
            int r = sl >> 4, gp = sl & 15, g = gp ^ (r & 15);
            gload_lds16(gAf + (size_t)r * D_ + kt * 64 + g * 4, smem + sl * 16);
        }
        // B: 1024 granules fp16 (2 heads x 512), r1's exact layout
#pragma unroll
        for (int j = 0; j < 2; ++j) {
            int sl = j * 512 + tid;
            int r = (sl & 511) >> 3, gp = sl & 7, g = gp ^ (r & 7);
            gload_lds16(gB + (size_t)(j * 64 + r) * D_ + kt * 64 + g * 8,
                        smem + 65536 + sl * 16);
        }
        __syncthreads();
#pragma unroll
        for (int ks = 0; ks < 2; ++ks) {
            const int gpB = ((ks * 4 + q4) ^ (l15 & 7)) * 16;
            half8 af[4], bf[4];
#pragma unroll
            for (int tt = 0; tt < 4; ++tt) {
                const int rt = tq * 64 + tt * 16 + l15;      // rt & 15 == l15
                const unsigned char* Ab = smem + rt * 256;
                const int g0 = (ks * 8 + 2 * q4) ^ l15;      // data granules
                const int g1 = g0 ^ 1;                       // (…+1)^l15
                const f32x4 va = *reinterpret_cast<const f32x4*>(Ab + g0 * 16);
                const f32x4 vb = *reinterpret_cast<const f32x4*>(Ab + g1 * 16);
                uint4 pk;
                pk.x = f2h2(va[0], va[1]);
                pk.y = f2h2(va[2], va[3]);
                pk.z = f2h2(vb[0], vb[1]);
                pk.w = f2h2(vb[2], vb[3]);
                af[tt] = __builtin_bit_cast(half8, pk);
            }
#pragma unroll
            for (int mt = 0; mt < 4; ++mt)
                bf[mt] = *reinterpret_cast<const half8*>(
                    smem + 65536 + hl * 8192 + (mt * 16 + l15) * 128 + gpB);
#pragma unroll
            for (int tt = 0; tt < 4; ++tt)
#pragma unroll
                for (int mt = 0; mt < 4; ++mt)
                    acc[tt][mt] = __builtin_amdgcn_mfma_f32_16x16x32_f16(
                        af[tt], bf[mt], acc[tt][mt], 0, 0, 0);
        }
    }

    // ======== softmax over m in registers (reduce over l15), no max-sub ====
#pragma unroll
    for (int tt = 0; tt < 4; ++tt)
#pragma unroll
        for (int rg = 0; rg < 4; ++rg) {
            float e0 = __expf(acc[tt][0][rg]);
            float e1 = __expf(acc[tt][1][rg]);
            float e2 = __expf(acc[tt][2][rg]);
            float e3 = __expf(acc[tt][3][rg]);
            float sm = (e0 + e1) + (e2 + e3);
#pragma unroll
            for (int msk = 1; msk <= 8; msk <<= 1)
                sm += __shfl_xor(sm, msk, 64);
            float inv = __builtin_amdgcn_rcpf(sm);
            acc[tt][0][rg] = e0 * inv;
            acc[tt][1][rg] = e1 * inv;
            acc[tt][2][rg] = e2 * inv;
            acc[tt][3][rg] = e3 * inv;
        }
    __syncthreads();   // score-phase frag reads done; wT/Hh alias A/B

    const int m_s = tid & 63;
    const int g8  = tid >> 6;    // segment index (== wv)

    // ======== per-head: pack wT -> suffix scan -> partial GEMM =============
    for (int head = 0; head < 2; ++head) {
        const int h = hp * 2 + head;
        const int chunkIdx = (b * NH_ + h) * CCH + c;

        // pack w -> wT[m][t] fp16, pitch 264 (this head's waves only)
        if (hl == head) {
#pragma unroll
            for (int tt = 0; tt < 4; ++tt)
#pragma unroll
                for (int mt = 0; mt < 4; ++mt) {
                    uint2 pk = {f2h2(acc[tt][mt][0], acc[tt][mt][1]),
                                f2h2(acc[tt][mt][2], acc[tt][mt][3])};
                    *reinterpret_cast<uint2*>(
                        wT + (mt * 16 + l15) * 264 + tq * 64 + tt * 16 + q4 * 4) = pk;
                }
        }
        // stage Hh: H fp32 [256t][64d] head slice -> f16 [d][t], pitch 264
        {
            const int dp = tid & 31, tg = tid >> 5;
            const float* src = Hf + (Hrow + tg * 16) * D_ + h * 64 + 2 * dp;
            unsigned short* dst0 = Hh + (2 * dp) * 264 + tg * 16;
            unsigned short* dst1 = Hh + (2 * dp + 1) * 264 + tg * 16;
#pragma unroll
            for (int i = 0; i < 8; ++i) {
                const float2 a = *reinterpret_cast<const float2*>(
                    src + (size_t)(2 * i) * D_);
                const float2 bb = *reinterpret_cast<const float2*>(
                    src + (size_t)(2 * i + 1) * D_);
                *reinterpret_cast<unsigned int*>(dst0 + 2 * i) = f2h2(a.x, bb.x);
                *reinterpret_cast<unsigned int*>(dst1 + 2 * i) = f2h2(a.y, bb.y);
            }
        }
        __syncthreads();

        // segmented suffix gate scan: 8 segments x 32 t, all 512 threads
        {
            unsigned short* rowp = wT + m_s * 264 + g8 * 32;
            float pband = 1.0f;
#pragma unroll
            for (int oct = 0; oct < 4; ++oct) {
                short8 v = *reinterpret_cast<const short8*>(rowp + oct * 8);
#pragma unroll
                for (int j = 0; j < 8; ++j)
                    pband *= fmaf(-ALPHA_, h2f((unsigned short)v[j]), 1.0f);
            }
            segprod[g8 * 64 + m_s] = pband;
            __syncthreads();
            float R = 1.0f;
#pragma unroll
            for (int gg = 1; gg < 8; ++gg)
                if (g8 + gg < 8) R *= segprod[(g8 + gg) * 64 + m_s];
            if (g8 == 0)
                chunkprod[(size_t)chunkIdx * 64 + m_s] = R * pband;
#pragma unroll
            for (int oct = 3; oct >= 0; --oct) {
                short8 v = *reinterpret_cast<const short8*>(rowp + oct * 8);
                short8 o;
#pragma unroll
                for (int j = 7; j >= 0; --j) {
                    float w = h2f((unsigned short)v[j]);
                    _Float16 we = (_Float16)(ALPHA_ * w * R);
                    o[j] = (short)__builtin_bit_cast(unsigned short, we);
                    R *= fmaf(-ALPHA_, w, 1.0f);
                }
                *reinterpret_cast<short8*>(rowp + oct * 8) = o;
            }
        }
        __syncthreads();   // w_eff + Hh visible

        // partial GEMM: pacc[m][d] += w_eff^T . H_head; wave = (mt=w&3, dh=w>>2)
        {
            const int mt = wv & 3;
            const int dh = wv >> 2;
            f32x4 pacc[2] = {};
#pragma unroll
            for (int ks = 0; ks < 8; ++ks) {
                half8 a = *reinterpret_cast<const half8*>(
                    wT + (mt * 16 + l15) * 264 + ks * 32 + q4 * 8);
#pragma unroll
                for (int dt = 0; dt < 2; ++dt) {
                    half8 bb = *reinterpret_cast<const half8*>(
                        Hh + (dh * 32 + dt * 16 + l15) * 264 + ks * 32 + q4 * 8);
                    pacc[dt] = __builtin_amdgcn_mfma_f32_16x16x32_f16(
                        a, bb, pacc[dt], 0, 0, 0);
                }
            }
#pragma unroll
            for (int dt = 0; dt < 2; ++dt)
#pragma unroll
                for (int rg = 0; rg < 4; ++rg)
                    partial[((size_t)chunkIdx * 64 + mt * 16 + q4 * 4 + rg) * 64
                            + dh * 32 + dt * 16 + l15] = pacc[dt][rg];
        }
        if (head == 0) __syncthreads();   // wT/Hh reuse for head 1
    }
}

// ---------------------------------------------------------------------------
// Kernel 2: combine 16 chunks; grid (12, 8, 4) — mg picks 16 m-rows.
// ---------------------------------------------------------------------------
__global__ __launch_bounds__(256) void k2(const float* __restrict__ chunkprod,
                                          const float* __restrict__ partial,
                                          const float* __restrict__ s0,
                                          float* __restrict__ out) {
    const int h = blockIdx.x;
    const int b = blockIdx.y;
    const int mg = blockIdx.z;
    const int tid = threadIdx.x;
    const int m  = mg * 16 + (tid >> 4);
    const int d0 = (tid & 15) * 4;

    const size_t cpBase = (size_t)(b * NH_ + h) * CCH;
    float sfx[CCH];
    float run = 1.0f;
#pragma unroll
    for (int c = CCH - 1; c >= 0; --c) {
        sfx[c] = run;
        run *= chunkprod[(cpBase + c) * M_ + m];
    }
    const float4 v0 = *reinterpret_cast<const float4*>(
        s0 + (size_t)m * D_ + h * 64 + d0);
    float4 acc = make_float4(v0.x * run, v0.y * run, v0.z * run, v0.w * run);
#pragma unroll
    for (int c = 0; c < CCH; ++c) {
        const float sv = sfx[c];
        const float4 pp = *reinterpret_cast<const float4*>(
            partial + ((cpBase + c) * M_ + m) * 64 + d0);
        acc.x = fmaf(sv, pp.x, acc.x);
        acc.y = fmaf(sv, pp.y, acc.y);
        acc.z = fmaf(sv, pp.z, acc.z);
        acc.w = fmaf(sv, pp.w, acc.w);
    }
    *reinterpret_cast<float4*>(out + (size_t)(b * M_ + m) * D_ + h * 64 + d0) = acc;
}

// ---------------------------------------------------------------------------
extern "C" void kernel_launch(void* const* d_in, const int* in_sizes, int n_in,
                              void* d_out, int out_size, void* d_ws, size_t ws_size,
                              hipStream_t stream) {
    const float* H     = (const float*)d_in[0];
    const float* proto = (const float*)d_in[1];
    const float* W     = (const float*)d_in[2];
    const float* s0    = (const float*)d_in[3];
    float* out = (float*)d_out;

    // ws: P16 u16[589824] (1.18 MB) | chunkprod f32[98304] (0.39 MB)
    //     | partial f32[6291456] (25.2 MB)   ~26.7 MB total
    unsigned short* P16 = (unsigned short*)d_ws;
    float* chunkprod = (float*)((unsigned char*)d_ws + 1179648);
    float* partial   = (float*)((unsigned char*)d_ws + 1572864);

    kP<<<dim3(6, NH_), 256, 0, stream>>>(proto, W, P16);
    k1<<<dim3(768), 512, LDS_BYTES, stream>>>(H, P16, chunkprod, partial);
    k2<<<dim3(NH_, B_, 4), 256, 0, stream>>>(chunkprod, partial, s0, out);
}

// Round 9
// 225.382 us; speedup vs baseline: 1.1725x; 1.0365x over previous
//
#include <hip/hip_runtime.h>

#define B_ 8
#define T_ 4096
#define D_ 768
#define NH_ 12
#define M_ 64
#define ALPHA_ 0.1f

#define CCH 16         // chunks over T
#define CHUNK_T 256    // t per block

using half8 = __attribute__((ext_vector_type(8))) _Float16;
using short8 = __attribute__((ext_vector_type(8))) short;
using f32x4 = __attribute__((ext_vector_type(4))) float;

__device__ __forceinline__ unsigned int f2h2(float a, float b) {
    unsigned short ua = __builtin_bit_cast(unsigned short, (_Float16)a);
    unsigned short ub = __builtin_bit_cast(unsigned short, (_Float16)b);
    return (unsigned int)ua | ((unsigned int)ub << 16);
}
__device__ __forceinline__ float h2f(unsigned short u) {
    return (float)__builtin_bit_cast(_Float16, u);
}
// async global->LDS, 16 B per lane; LDS dst must be wave-uniform base + lane*16
__device__ __forceinline__ void gload_lds16(const void* g, void* l) {
    __builtin_amdgcn_global_load_lds(
        (const __attribute__((address_space(1))) unsigned int*)g,
        (__attribute__((address_space(3))) unsigned int*)l, 16, 0, 0);
}

// ---------------------------------------------------------------------------
// Kernel kPre: fused preprocessing.
//   blocks [0,12288): H fp32 -> fp16, 8 floats/thread: 2x float4 load +
//     ONE lane-contiguous uint4 store (16 B/lane). The old 8-B uint2 stores
//     ran the kernel at 3.1 TB/s (measured ~48.5 us by timeline fit);
//     16-B store coalescing targets ~5.5-6 TB/s (~26 us).
//   blocks [12288,12360): P[h,m,e] = (1/8) * proto[m,:] . W[:,e] -> fp16.
// dyn LDS 49152 B (kP-part only; H16-part 3 blk/CU = 12 waves -> ~49 KB of
// loads in flight per CU, far above the ~4 KB needed to saturate HBM).
// ---------------------------------------------------------------------------
__global__ __launch_bounds__(256) void kPre(const float* __restrict__ H,
                                            const float* __restrict__ proto,
                                            const float* __restrict__ W,
                                            unsigned short* __restrict__ H16,
                                            unsigned short* __restrict__ P16) {
    const int tid = threadIdx.x;
    if (blockIdx.x < 12288) {
        const size_t base = ((size_t)blockIdx.x * 256 + tid) * 8;  // float idx
        const float4 v0 = *reinterpret_cast<const float4*>(H + base);
        const float4 v1 = *reinterpret_cast<const float4*>(H + base + 4);
        uint4 pk;
        pk.x = f2h2(v0.x, v0.y);
        pk.y = f2h2(v0.z, v0.w);
        pk.z = f2h2(v1.x, v1.y);
        pk.w = f2h2(v1.z, v1.w);
        *reinterpret_cast<uint4*>(H16 + base) = pk;
        return;
    }

    // ---- kP part ----
    extern __shared__ __align__(16) unsigned char smem_u8[];
    float* Ws = (float*)smem_u8;             // [64][128] = 32768 B
    float* Ks = (float*)(smem_u8 + 32768);   // [64][64]  = 16384 B
    const int q = blockIdx.x - 12288;
    const int et = q % 6;
    const int h  = q / 6;

#pragma unroll
    for (int j = 0; j < 8; ++j) {
        int f = tid + j * 256;
        int i = f >> 5, c4 = f & 31;
        const float4 v = *reinterpret_cast<const float4*>(
            W + (size_t)(h * 64 + i) * D_ + et * 128 + c4 * 4);
        *reinterpret_cast<float4*>(&Ws[i * 128 + c4 * 4]) = v;
    }
#pragma unroll
    for (int j = 0; j < 4; ++j) {
        int f = tid + j * 256;
        int m = f >> 4, i4 = f & 15;
        const float4 v = *reinterpret_cast<const float4*>(
            proto + (size_t)m * D_ + h * 64 + i4 * 4);
        Ks[(i4 * 4 + 0) * 64 + m] = v.x;
        Ks[(i4 * 4 + 1) * 64 + m] = v.y;
        Ks[(i4 * 4 + 2) * 64 + m] = v.z;
        Ks[(i4 * 4 + 3) * 64 + m] = v.w;
    }
    __syncthreads();

    const int m0 = (tid >> 5) * 8;
    const int e0 = (tid & 31) * 4;
    float acc[8][4];
#pragma unroll
    for (int i = 0; i < 8; ++i)
#pragma unroll
        for (int j = 0; j < 4; ++j) acc[i][j] = 0.f;

    for (int i = 0; i < 64; ++i) {
        const float4 bb = *reinterpret_cast<const float4*>(&Ws[i * 128 + e0]);
        const float4 a0 = *reinterpret_cast<const float4*>(&Ks[i * 64 + m0]);
        const float4 a1 = *reinterpret_cast<const float4*>(&Ks[i * 64 + m0 + 4]);
        const float a[8] = {a0.x, a0.y, a0.z, a0.w, a1.x, a1.y, a1.z, a1.w};
#pragma unroll
        for (int mi = 0; mi < 8; ++mi) {
            acc[mi][0] = fmaf(a[mi], bb.x, acc[mi][0]);
            acc[mi][1] = fmaf(a[mi], bb.y, acc[mi][1]);
            acc[mi][2] = fmaf(a[mi], bb.z, acc[mi][2]);
            acc[mi][3] = fmaf(a[mi], bb.w, acc[mi][3]);
        }
    }
#pragma unroll
    for (int mi = 0; mi < 8; ++mi) {
        size_t idx = (size_t)(h * 64 + m0 + mi) * D_ + et * 128 + e0;
        uint2 pk = {f2h2(acc[mi][0] * 0.125f, acc[mi][1] * 0.125f),
                    f2h2(acc[mi][2] * 0.125f, acc[mi][3] * 0.125f)};
        *reinterpret_cast<uint2*>(P16 + idx) = pk;
    }
}

// ---------------------------------------------------------------------------
// Kernel 1: per (chunk=256t, head-PAIR, batch). 512 threads / 8 waves; wave w
// owns (head_local = w>>2, t-quarter = w&3). EXACT r1 structure (measured
// best: 61.6-62.7 us, 1.97M conflicts). BK=64 single-buffer DMA staging of
// fp16 H16 — all variants measured worse: BK=32 dbuf (r2/r3, conflicts 3.4x),
// occupancy+tail-split (r4), fused fp32-A reg-prefetch (r6/r7, spills),
// fused fp32-A DMA (r8, +50us: 2x staging bytes + cold-HBM first touch).
// grid 768 (b = p&7 pins batch per XCD), dyn LDS 69632 B, 2 blocks/CU.
//
// LDS (bytes): [0,32768) A f16[256t][64k] swz | [32768,49152) B f16[2h][64m][64k]
//   alias: [0,33792) wT f16[64m][264t] | [33792,67584) Hh f16[64d][264t]
//   [67584,69632) segprod f32[8][64]
// ---------------------------------------------------------------------------
#define LDS_BYTES 69632

__global__ __launch_bounds__(512, 4) void k1(const unsigned short* __restrict__ H16,
                                             const unsigned short* __restrict__ P16,
                                             float* __restrict__ chunkprod,
                                             float* __restrict__ partial) {
    const int p = blockIdx.x;
    const int b = p & 7;
    const int s = p >> 3;
    const int hp = s % 6;          // head pair index
    const int c  = s / 6;
    const int tid = threadIdx.x;
    const int wv  = tid >> 6;      // 0..7
    const int lane = tid & 63;
    const int l15 = lane & 15;
    const int q4  = lane >> 4;
    const int hl  = wv >> 2;       // wave's head_local (0/1)
    const int tq  = wv & 3;        // wave's t-quarter

    extern __shared__ __align__(16) unsigned char smem[];
    unsigned short* wT = (unsigned short*)(smem);
    unsigned short* Hh = (unsigned short*)(smem + 33792);
    float* segprod = (float*)(smem + 67584);

    const size_t Hrow = (size_t)(b * T_ + c * CHUNK_T);
    const unsigned short* gA = H16 + Hrow * D_;
    const unsigned short* gB = P16 + (size_t)(hp * 2) * 64 * D_;

    // ======== score GEMM: 256t x (2h x 64m), K=768, fp16, DMA-staged ========
    f32x4 acc[4][4] = {};   // t = tq*64+tt*16+q4*4+rg (row), m = mt*16+l15 (col)

    for (int kt = 0; kt < 12; ++kt) {
        __syncthreads();
        // A: 2048 granules of 16 B; slot sl -> row r=sl>>3, lds-granule gp=sl&7,
        // fetched data granule g = gp ^ (r&7)
#pragma unroll
        for (int j = 0; j < 4; ++j) {
            int sl = j * 512 + tid;
            int r = sl >> 3, gp = sl & 7, g = gp ^ (r & 7);
            gload_lds16(gA + (size_t)r * D_ + kt * 64 + g * 8, smem + sl * 16);
        }
        // B: 1024 granules (2 heads x 512)
#pragma unroll
        for (int j = 0; j < 2; ++j) {
            int sl = j * 512 + tid;
            int r = (sl & 511) >> 3, gp = sl & 7, g = gp ^ (r & 7);
            gload_lds16(gB + (size_t)(j * 64 + r) * D_ + kt * 64 + g * 8,
                        smem + 32768 + sl * 16);
        }
        __syncthreads();
#pragma unroll
        for (int ks = 0; ks < 2; ++ks) {
            const int gp = ((ks * 4 + q4) ^ (l15 & 7)) * 16;
            half8 af[4], bf[4];
#pragma unroll
            for (int tt = 0; tt < 4; ++tt)
                af[tt] = *reinterpret_cast<const half8*>(
                    smem + (tq * 64 + tt * 16 + l15) * 128 + gp);
#pragma unroll
            for (int mt = 0; mt < 4; ++mt)
                bf[mt] = *reinterpret_cast<const half8*>(
                    smem + 32768 + hl * 8192 + (mt * 16 + l15) * 128 + gp);
#pragma unroll
            for (int tt = 0; tt < 4; ++tt)
#pragma unroll
                for (int mt = 0; mt < 4; ++mt)
                    acc[tt][mt] = __builtin_amdgcn_mfma_f32_16x16x32_f16(
                        af[tt], bf[mt], acc[tt][mt], 0, 0, 0);
        }
    }

    // ======== softmax over m in registers (reduce over l15), no max-sub ====
#pragma unroll
    for (int tt = 0; tt < 4; ++tt)
#pragma unroll
        for (int rg = 0; rg < 4; ++rg) {
            float e0 = __expf(acc[tt][0][rg]);
            float e1 = __expf(acc[tt][1][rg]);
            float e2 = __expf(acc[tt][2][rg]);
            float e3 = __expf(acc[tt][3][rg]);
            float sm = (e0 + e1) + (e2 + e3);
#pragma unroll
            for (int msk = 1; msk <= 8; msk <<= 1)
                sm += __shfl_xor(sm, msk, 64);
            float inv = __builtin_amdgcn_rcpf(sm);
            acc[tt][0][rg] = e0 * inv;
            acc[tt][1][rg] = e1 * inv;
            acc[tt][2][rg] = e2 * inv;
            acc[tt][3][rg] = e3 * inv;
        }
    __syncthreads();   // score-phase frag reads done; wT/Hh alias A/B

    const int m_s = tid & 63;
    const int g8  = tid >> 6;    // segment index (== wv)

    // ======== per-head: pack wT -> suffix scan -> partial GEMM =============
    for (int head = 0; head < 2; ++head) {
        const int h = hp * 2 + head;
        const int chunkIdx = (b * NH_ + h) * CCH + c;

        // pack w -> wT[m][t] fp16, pitch 264 (this head's waves only)
        if (hl == head) {
#pragma unroll
            for (int tt = 0; tt < 4; ++tt)
#pragma unroll
                for (int mt = 0; mt < 4; ++mt) {
                    uint2 pk = {f2h2(acc[tt][mt][0], acc[tt][mt][1]),
                                f2h2(acc[tt][mt][2], acc[tt][mt][3])};
                    *reinterpret_cast<uint2*>(
                        wT + (mt * 16 + l15) * 264 + tq * 64 + tt * 16 + q4 * 4) = pk;
                }
        }
        // stage Hh: H16[256t][64d] head slice -> [d][t], pitch 264 (all threads)
        {
            const int dp = tid & 31, tg = tid >> 5;
            const unsigned short* src = H16 + (Hrow + tg * 16) * D_ + h * 64 + 2 * dp;
            unsigned short* dst0 = Hh + (2 * dp) * 264 + tg * 16;
            unsigned short* dst1 = Hh + (2 * dp + 1) * 264 + tg * 16;
#pragma unroll
            for (int i = 0; i < 8; ++i) {
                unsigned int a = *reinterpret_cast<const unsigned int*>(
                    src + (size_t)(2 * i) * D_);
                unsigned int bb = *reinterpret_cast<const unsigned int*>(
                    src + (size_t)(2 * i + 1) * D_);
                *reinterpret_cast<unsigned int*>(dst0 + 2 * i) =
                    (a & 0xffffu) | (bb << 16);
                *reinterpret_cast<unsigned int*>(dst1 + 2 * i) =
                    (a >> 16) | (bb & 0xffff0000u);
            }
        }
        __syncthreads();

        // segmented suffix gate scan: 8 segments x 32 t, all 512 threads
        {
            unsigned short* rowp = wT + m_s * 264 + g8 * 32;
            float pband = 1.0f;
#pragma unroll
            for (int oct = 0; oct < 4; ++oct) {
                short8 v = *reinterpret_cast<const short8*>(rowp + oct * 8);
#pragma unroll
                for (int j = 0; j < 8; ++j)
                    pband *= fmaf(-ALPHA_, h2f((unsigned short)v[j]), 1.0f);
            }
            segprod[g8 * 64 + m_s] = pband;
            __syncthreads();
            float R = 1.0f;
#pragma unroll
            for (int gg = 1; gg < 8; ++gg)
                if (g8 + gg < 8) R *= segprod[(g8 + gg) * 64 + m_s];
            if (g8 == 0)
                chunkprod[(size_t)chunkIdx * 64 + m_s] = R * pband;
#pragma unroll
            for (int oct = 3; oct >= 0; --oct) {
                short8 v = *reinterpret_cast<const short8*>(rowp + oct * 8);
                short8 o;
#pragma unroll
                for (int j = 7; j >= 0; --j) {
                    float w = h2f((unsigned short)v[j]);
                    _Float16 we = (_Float16)(ALPHA_ * w * R);
                    o[j] = (short)__builtin_bit_cast(unsigned short, we);
                    R *= fmaf(-ALPHA_, w, 1.0f);
                }
                *reinterpret_cast<short8*>(rowp + oct * 8) = o;
            }
        }
        __syncthreads();   // w_eff + Hh visible

        // partial GEMM: pacc[m][d] += w_eff^T . H_head; wave = (mt=w&3, dh=w>>2)
        {
            const int mt = wv & 3;
            const int dh = wv >> 2;
            f32x4 pacc[2] = {};
#pragma unroll
            for (int ks = 0; ks < 8; ++ks) {
                half8 a = *reinterpret_cast<const half8*>(
                    wT + (mt * 16 + l15) * 264 + ks * 32 + q4 * 8);
#pragma unroll
                for (int dt = 0; dt < 2; ++dt) {
                    half8 bb = *reinterpret_cast<const half8*>(
                        Hh + (dh * 32 + dt * 16 + l15) * 264 + ks * 32 + q4 * 8);
                    pacc[dt] = __builtin_amdgcn_mfma_f32_16x16x32_f16(
                        a, bb, pacc[dt], 0, 0, 0);
                }
            }
#pragma unroll
            for (int dt = 0; dt < 2; ++dt)
#pragma unroll
                for (int rg = 0; rg < 4; ++rg)
                    partial[((size_t)chunkIdx * 64 + mt * 16 + q4 * 4 + rg) * 64
                            + dh * 32 + dt * 16 + l15] = pacc[dt][rg];
        }
        if (head == 0) __syncthreads();   // wT/Hh reuse for head 1
    }
}

// ---------------------------------------------------------------------------
// Kernel 2: combine 16 chunks; grid (12, 8, 4) — mg picks 16 m-rows.
// ---------------------------------------------------------------------------
__global__ __launch_bounds__(256) void k2(const float* __restrict__ chunkprod,
                                          const float* __restrict__ partial,
                                          const float* __restrict__ s0,
                                          float* __restrict__ out) {
    const int h = blockIdx.x;
    const int b = blockIdx.y;
    const int mg = blockIdx.z;
    const int tid = threadIdx.x;
    const int m  = mg * 16 + (tid >> 4);
    const int d0 = (tid & 15) * 4;

    const size_t cpBase = (size_t)(b * NH_ + h) * CCH;
    float sfx[CCH];
    float run = 1.0f;
#pragma unroll
    for (int c = CCH - 1; c >= 0; --c) {
        sfx[c] = run;
        run *= chunkprod[(cpBase + c) * M_ + m];
    }
    const float4 v0 = *reinterpret_cast<const float4*>(
        s0 + (size_t)m * D_ + h * 64 + d0);
    float4 acc = make_float4(v0.x * run, v0.y * run, v0.z * run, v0.w * run);
#pragma unroll
    for (int c = 0; c < CCH; ++c) {
        const float sv = sfx[c];
        const float4 pp = *reinterpret_cast<const float4*>(
            partial + ((cpBase + c) * M_ + m) * 64 + d0);
        acc.x = fmaf(sv, pp.x, acc.x);
        acc.y = fmaf(sv, pp.y, acc.y);
        acc.z = fmaf(sv, pp.z, acc.z);
        acc.w = fmaf(sv, pp.w, acc.w);
    }
    *reinterpret_cast<float4*>(out + (size_t)(b * M_ + m) * D_ + h * 64 + d0) = acc;
}

// ---------------------------------------------------------------------------
extern "C" void kernel_launch(void* const* d_in, const int* in_sizes, int n_in,
                              void* d_out, int out_size, void* d_ws, size_t ws_size,
                              hipStream_t stream) {
    const float* H     = (const float*)d_in[0];
    const float* proto = (const float*)d_in[1];
    const float* W     = (const float*)d_in[2];
    const float* s0    = (const float*)d_in[3];
    float* out = (float*)d_out;

    // ws: H16 u16[25165824] (50.3 MB) | P16 u16[589824] (1.18 MB)
    //     | chunkprod f32[98304] | partial f32[6291456] (25.2 MB)   ~77 MB
    unsigned short* H16 = (unsigned short*)d_ws;
    unsigned short* P16 = (unsigned short*)((unsigned char*)d_ws + 50331648);
    float* chunkprod = (float*)((unsigned char*)d_ws + 51511296);
    float* partial   = (float*)((unsigned char*)d_ws + 51904512);

    kPre<<<dim3(12360), 256, 49152, stream>>>(H, proto, W, H16, P16);
    k1<<<dim3(768), 512, LDS_BYTES, stream>>>(H16, P16, chunkprod, partial);
    k2<<<dim3(NH_, B_, 4), 256, 0, stream>>>(chunkprod, partial, s0, out);
}

// Round 10
// 221.574 us; speedup vs baseline: 1.1926x; 1.0172x over previous
//
#include <hip/hip_runtime.h>

#define B_ 8
#define T_ 4096
#define D_ 768
#define NH_ 12
#define M_ 64
#define ALPHA_ 0.1f

#define CCH 16         // chunks over T
#define CHUNK_T 256    // t per block

using half8 = __attribute__((ext_vector_type(8))) _Float16;
using short8 = __attribute__((ext_vector_type(8))) short;
using f32x4 = __attribute__((ext_vector_type(4))) float;

__device__ __forceinline__ unsigned int f2h2(float a, float b) {
    unsigned short ua = __builtin_bit_cast(unsigned short, (_Float16)a);
    unsigned short ub = __builtin_bit_cast(unsigned short, (_Float16)b);
    return (unsigned int)ua | ((unsigned int)ub << 16);
}
__device__ __forceinline__ float h2f(unsigned short u) {
    return (float)__builtin_bit_cast(_Float16, u);
}
// async global->LDS, 16 B per lane; LDS dst must be wave-uniform base + lane*16
__device__ __forceinline__ void gload_lds16(const void* g, void* l) {
    __builtin_amdgcn_global_load_lds(
        (const __attribute__((address_space(1))) unsigned int*)g,
        (__attribute__((address_space(3))) unsigned int*)l, 16, 0, 0);
}

// ---------------------------------------------------------------------------
// Kernel kH16: H fp32 -> fp16. SEPARATE launch with ZERO dyn LDS (8 blk/CU,
// ~64 KB loads in flight per CU) + 16-B stores (8 floats/thread). The r9
// merged version carried a 49 KB dyn-LDS alloc on every streaming block
// (3 blk/CU, marginal latency coverage); r1's separate version had 8-B
// stores. This is the first round combining both fixes.
// ---------------------------------------------------------------------------
__global__ __launch_bounds__(256) void kH16(const float* __restrict__ H,
                                            unsigned short* __restrict__ H16) {
    const size_t base = ((size_t)blockIdx.x * 256 + threadIdx.x) * 8;  // float idx
    const float4 v0 = *reinterpret_cast<const float4*>(H + base);
    const float4 v1 = *reinterpret_cast<const float4*>(H + base + 4);
    uint4 pk;
    pk.x = f2h2(v0.x, v0.y);
    pk.y = f2h2(v0.z, v0.w);
    pk.z = f2h2(v1.x, v1.y);
    pk.w = f2h2(v1.z, v1.w);
    *reinterpret_cast<uint4*>(H16 + base) = pk;
}

// ---------------------------------------------------------------------------
// Kernel kP: P[h,m,e] = (1/8) * sum_i proto[m, h*64+i] * W[h*64+i, e] -> fp16.
// ---------------------------------------------------------------------------
__global__ __launch_bounds__(256) void kP(const float* __restrict__ proto,
                                          const float* __restrict__ W,
                                          unsigned short* __restrict__ P16) {
    const int et = blockIdx.x;
    const int h  = blockIdx.y;
    const int tid = threadIdx.x;

    __shared__ __align__(16) float Ws[64 * 128];
    __shared__ __align__(16) float Ks[64 * 64];

#pragma unroll
    for (int j = 0; j < 8; ++j) {
        int f = tid + j * 256;
        int i = f >> 5, c4 = f & 31;
        const float4 v = *reinterpret_cast<const float4*>(
            W + (size_t)(h * 64 + i) * D_ + et * 128 + c4 * 4);
        *reinterpret_cast<float4*>(&Ws[i * 128 + c4 * 4]) = v;
    }
#pragma unroll
    for (int j = 0; j < 4; ++j) {
        int f = tid + j * 256;
        int m = f >> 4, i4 = f & 15;
        const float4 v = *reinterpret_cast<const float4*>(
            proto + (size_t)m * D_ + h * 64 + i4 * 4);
        Ks[(i4 * 4 + 0) * 64 + m] = v.x;
        Ks[(i4 * 4 + 1) * 64 + m] = v.y;
        Ks[(i4 * 4 + 2) * 64 + m] = v.z;
        Ks[(i4 * 4 + 3) * 64 + m] = v.w;
    }
    __syncthreads();

    const int m0 = (tid >> 5) * 8;
    const int e0 = (tid & 31) * 4;
    float acc[8][4];
#pragma unroll
    for (int i = 0; i < 8; ++i)
#pragma unroll
        for (int j = 0; j < 4; ++j) acc[i][j] = 0.f;

    for (int i = 0; i < 64; ++i) {
        const float4 bb = *reinterpret_cast<const float4*>(&Ws[i * 128 + e0]);
        const float4 a0 = *reinterpret_cast<const float4*>(&Ks[i * 64 + m0]);
        const float4 a1 = *reinterpret_cast<const float4*>(&Ks[i * 64 + m0 + 4]);
        const float a[8] = {a0.x, a0.y, a0.z, a0.w, a1.x, a1.y, a1.z, a1.w};
#pragma unroll
        for (int mi = 0; mi < 8; ++mi) {
            acc[mi][0] = fmaf(a[mi], bb.x, acc[mi][0]);
            acc[mi][1] = fmaf(a[mi], bb.y, acc[mi][1]);
            acc[mi][2] = fmaf(a[mi], bb.z, acc[mi][2]);
            acc[mi][3] = fmaf(a[mi], bb.w, acc[mi][3]);
        }
    }
#pragma unroll
    for (int mi = 0; mi < 8; ++mi) {
        size_t idx = (size_t)(h * 64 + m0 + mi) * D_ + et * 128 + e0;
        uint2 pk = {f2h2(acc[mi][0] * 0.125f, acc[mi][1] * 0.125f),
                    f2h2(acc[mi][2] * 0.125f, acc[mi][3] * 0.125f)};
        *reinterpret_cast<uint2*>(P16 + idx) = pk;
    }
}

// ---------------------------------------------------------------------------
// Kernel 1: per (chunk=256t, head-PAIR, batch). 512 threads / 8 waves; wave w
// owns (head_local = w>>2, t-quarter = w&3). EXACT r1 structure (measured
// best: 61.3-62.7 us, conflicts 1,966,080 stable across runs). BK=64
// single-buffer DMA staging of fp16 H16 — all variants measured worse:
// BK=32 dbuf (r2/r3), tail-split occupancy (r4), fused fp32-A (r6/r7/r8).
// grid 768 (b = p&7 pins batch per XCD), dyn LDS 69632 B, 2 blocks/CU.
//
// LDS (bytes): [0,32768) A f16[256t][64k] swz | [32768,49152) B f16[2h][64m][64k]
//   alias: [0,33792) wT f16[64m][264t] | [33792,67584) Hh f16[64d][264t]
//   [67584,69632) segprod f32[8][64]
// ---------------------------------------------------------------------------
#define LDS_BYTES 69632

__global__ __launch_bounds__(512, 4) void k1(const unsigned short* __restrict__ H16,
                                             const unsigned short* __restrict__ P16,
                                             float* __restrict__ chunkprod,
                                             float* __restrict__ partial) {
    const int p = blockIdx.x;
    const int b = p & 7;
    const int s = p >> 3;
    const int hp = s % 6;          // head pair index
    const int c  = s / 6;
    const int tid = threadIdx.x;
    const int wv  = tid >> 6;      // 0..7
    const int lane = tid & 63;
    const int l15 = lane & 15;
    const int q4  = lane >> 4;
    const int hl  = wv >> 2;       // wave's head_local (0/1)
    const int tq  = wv & 3;        // wave's t-quarter

    extern __shared__ __align__(16) unsigned char smem[];
    unsigned short* wT = (unsigned short*)(smem);
    unsigned short* Hh = (unsigned short*)(smem + 33792);
    float* segprod = (float*)(smem + 67584);

    const size_t Hrow = (size_t)(b * T_ + c * CHUNK_T);
    const unsigned short* gA = H16 + Hrow * D_;
    const unsigned short* gB = P16 + (size_t)(hp * 2) * 64 * D_;

    // ======== score GEMM: 256t x (2h x 64m), K=768, fp16, DMA-staged ========
    f32x4 acc[4][4] = {};   // t = tq*64+tt*16+q4*4+rg (row), m = mt*16+l15 (col)

    for (int kt = 0; kt < 12; ++kt) {
        __syncthreads();
        // A: 2048 granules of 16 B; slot sl -> row r=sl>>3, lds-granule gp=sl&7,
        // fetched data granule g = gp ^ (r&7)
#pragma unroll
        for (int j = 0; j < 4; ++j) {
            int sl = j * 512 + tid;
            int r = sl >> 3, gp = sl & 7, g = gp ^ (r & 7);
            gload_lds16(gA + (size_t)r * D_ + kt * 64 + g * 8, smem + sl * 16);
        }
        // B: 1024 granules (2 heads x 512)
#pragma unroll
        for (int j = 0; j < 2; ++j) {
            int sl = j * 512 + tid;
            int r = (sl & 511) >> 3, gp = sl & 7, g = gp ^ (r & 7);
            gload_lds16(gB + (size_t)(j * 64 + r) * D_ + kt * 64 + g * 8,
                        smem + 32768 + sl * 16);
        }
        __syncthreads();
#pragma unroll
        for (int ks = 0; ks < 2; ++ks) {
            const int gp = ((ks * 4 + q4) ^ (l15 & 7)) * 16;
            half8 af[4], bf[4];
#pragma unroll
            for (int tt = 0; tt < 4; ++tt)
                af[tt] = *reinterpret_cast<const half8*>(
                    smem + (tq * 64 + tt * 16 + l15) * 128 + gp);
#pragma unroll
            for (int mt = 0; mt < 4; ++mt)
                bf[mt] = *reinterpret_cast<const half8*>(
                    smem + 32768 + hl * 8192 + (mt * 16 + l15) * 128 + gp);
#pragma unroll
            for (int tt = 0; tt < 4; ++tt)
#pragma unroll
                for (int mt = 0; mt < 4; ++mt)
                    acc[tt][mt] = __builtin_amdgcn_mfma_f32_16x16x32_f16(
                        af[tt], bf[mt], acc[tt][mt], 0, 0, 0);
        }
    }

    // ======== softmax over m in registers (reduce over l15), no max-sub ====
#pragma unroll
    for (int tt = 0; tt < 4; ++tt)
#pragma unroll
        for (int rg = 0; rg < 4; ++rg) {
            float e0 = __expf(acc[tt][0][rg]);
            float e1 = __expf(acc[tt][1][rg]);
            float e2 = __expf(acc[tt][2][rg]);
            float e3 = __expf(acc[tt][3][rg]);
            float sm = (e0 + e1) + (e2 + e3);
#pragma unroll
            for (int msk = 1; msk <= 8; msk <<= 1)
                sm += __shfl_xor(sm, msk, 64);
            float inv = __builtin_amdgcn_rcpf(sm);
            acc[tt][0][rg] = e0 * inv;
            acc[tt][1][rg] = e1 * inv;
            acc[tt][2][rg] = e2 * inv;
            acc[tt][3][rg] = e3 * inv;
        }
    __syncthreads();   // score-phase frag reads done; wT/Hh alias A/B

    const int m_s = tid & 63;
    const int g8  = tid >> 6;    // segment index (== wv)

    // ======== per-head: pack wT -> suffix scan -> partial GEMM =============
    for (int head = 0; head < 2; ++head) {
        const int h = hp * 2 + head;
        const int chunkIdx = (b * NH_ + h) * CCH + c;

        // pack w -> wT[m][t] fp16, pitch 264 (this head's waves only)
        if (hl == head) {
#pragma unroll
            for (int tt = 0; tt < 4; ++tt)
#pragma unroll
                for (int mt = 0; mt < 4; ++mt) {
                    uint2 pk = {f2h2(acc[tt][mt][0], acc[tt][mt][1]),
                                f2h2(acc[tt][mt][2], acc[tt][mt][3])};
                    *reinterpret_cast<uint2*>(
                        wT + (mt * 16 + l15) * 264 + tq * 64 + tt * 16 + q4 * 4) = pk;
                }
        }
        // stage Hh: H16[256t][64d] head slice -> [d][t], pitch 264 (all threads)
        {
            const int dp = tid & 31, tg = tid >> 5;
            const unsigned short* src = H16 + (Hrow + tg * 16) * D_ + h * 64 + 2 * dp;
            unsigned short* dst0 = Hh + (2 * dp) * 264 + tg * 16;
            unsigned short* dst1 = Hh + (2 * dp + 1) * 264 + tg * 16;
#pragma unroll
            for (int i = 0; i < 8; ++i) {
                unsigned int a = *reinterpret_cast<const unsigned int*>(
                    src + (size_t)(2 * i) * D_);
                unsigned int bb = *reinterpret_cast<const unsigned int*>(
                    src + (size_t)(2 * i + 1) * D_);
                *reinterpret_cast<unsigned int*>(dst0 + 2 * i) =
                    (a & 0xffffu) | (bb << 16);
                *reinterpret_cast<unsigned int*>(dst1 + 2 * i) =
                    (a >> 16) | (bb & 0xffff0000u);
            }
        }
        __syncthreads();

        // segmented suffix gate scan: 8 segments x 32 t, all 512 threads
        {
            unsigned short* rowp = wT + m_s * 264 + g8 * 32;
            float pband = 1.0f;
#pragma unroll
            for (int oct = 0; oct < 4; ++oct) {
                short8 v = *reinterpret_cast<const short8*>(rowp + oct * 8);
#pragma unroll
                for (int j = 0; j < 8; ++j)
                    pband *= fmaf(-ALPHA_, h2f((unsigned short)v[j]), 1.0f);
            }
            segprod[g8 * 64 + m_s] = pband;
            __syncthreads();
            float R = 1.0f;
#pragma unroll
            for (int gg = 1; gg < 8; ++gg)
                if (g8 + gg < 8) R *= segprod[(g8 + gg) * 64 + m_s];
            if (g8 == 0)
                chunkprod[(size_t)chunkIdx * 64 + m_s] = R * pband;
#pragma unroll
            for (int oct = 3; oct >= 0; --oct) {
                short8 v = *reinterpret_cast<const short8*>(rowp + oct * 8);
                short8 o;
#pragma unroll
                for (int j = 7; j >= 0; --j) {
                    float w = h2f((unsigned short)v[j]);
                    _Float16 we = (_Float16)(ALPHA_ * w * R);
                    o[j] = (short)__builtin_bit_cast(unsigned short, we);
                    R *= fmaf(-ALPHA_, w, 1.0f);
                }
                *reinterpret_cast<short8*>(rowp + oct * 8) = o;
            }
        }
        __syncthreads();   // w_eff + Hh visible

        // partial GEMM: pacc[m][d] += w_eff^T . H_head; wave = (mt=w&3, dh=w>>2)
        {
            const int mt = wv & 3;
            const int dh = wv >> 2;
            f32x4 pacc[2] = {};
#pragma unroll
            for (int ks = 0; ks < 8; ++ks) {
                half8 a = *reinterpret_cast<const half8*>(
                    wT + (mt * 16 + l15) * 264 + ks * 32 + q4 * 8);
#pragma unroll
                for (int dt = 0; dt < 2; ++dt) {
                    half8 bb = *reinterpret_cast<const half8*>(
                        Hh + (dh * 32 + dt * 16 + l15) * 264 + ks * 32 + q4 * 8);
                    pacc[dt] = __builtin_amdgcn_mfma_f32_16x16x32_f16(
                        a, bb, pacc[dt], 0, 0, 0);
                }
            }
#pragma unroll
            for (int dt = 0; dt < 2; ++dt)
#pragma unroll
                for (int rg = 0; rg < 4; ++rg)
                    partial[((size_t)chunkIdx * 64 + mt * 16 + q4 * 4 + rg) * 64
                            + dh * 32 + dt * 16 + l15] = pacc[dt][rg];
        }
        if (head == 0) __syncthreads();   // wT/Hh reuse for head 1
    }
}

// ---------------------------------------------------------------------------
// Kernel 2: combine 16 chunks; grid (12, 8, 4) — mg picks 16 m-rows.
// ---------------------------------------------------------------------------
__global__ __launch_bounds__(256) void k2(const float* __restrict__ chunkprod,
                                          const float* __restrict__ partial,
                                          const float* __restrict__ s0,
                                          float* __restrict__ out) {
    const int h = blockIdx.x;
    const int b = blockIdx.y;
    const int mg = blockIdx.z;
    const int tid = threadIdx.x;
    const int m  = mg * 16 + (tid >> 4);
    const int d0 = (tid & 15) * 4;

    const size_t cpBase = (size_t)(b * NH_ + h) * CCH;
    float sfx[CCH];
    float run = 1.0f;
#pragma unroll
    for (int c = CCH - 1; c >= 0; --c) {
        sfx[c] = run;
        run *= chunkprod[(cpBase + c) * M_ + m];
    }
    const float4 v0 = *reinterpret_cast<const float4*>(
        s0 + (size_t)m * D_ + h * 64 + d0);
    float4 acc = make_float4(v0.x * run, v0.y * run, v0.z * run, v0.w * run);
#pragma unroll
    for (int c = 0; c < CCH; ++c) {
        const float sv = sfx[c];
        const float4 pp = *reinterpret_cast<const float4*>(
            partial + ((cpBase + c) * M_ + m) * 64 + d0);
        acc.x = fmaf(sv, pp.x, acc.x);
        acc.y = fmaf(sv, pp.y, acc.y);
        acc.z = fmaf(sv, pp.z, acc.z);
        acc.w = fmaf(sv, pp.w, acc.w);
    }
    *reinterpret_cast<float4*>(out + (size_t)(b * M_ + m) * D_ + h * 64 + d0) = acc;
}

// ---------------------------------------------------------------------------
extern "C" void kernel_launch(void* const* d_in, const int* in_sizes, int n_in,
                              void* d_out, int out_size, void* d_ws, size_t ws_size,
                              hipStream_t stream) {
    const float* H     = (const float*)d_in[0];
    const float* proto = (const float*)d_in[1];
    const float* W     = (const float*)d_in[2];
    const float* s0    = (const float*)d_in[3];
    float* out = (float*)d_out;

    // ws: H16 u16[25165824] (50.3 MB) | P16 u16[589824] (1.18 MB)
    //     | chunkprod f32[98304] | partial f32[6291456] (25.2 MB)   ~77 MB
    unsigned short* H16 = (unsigned short*)d_ws;
    unsigned short* P16 = (unsigned short*)((unsigned char*)d_ws + 50331648);
    float* chunkprod = (float*)((unsigned char*)d_ws + 51511296);
    float* partial   = (float*)((unsigned char*)d_ws + 51904512);

    kH16<<<dim3(12288), 256, 0, stream>>>(H, H16);
    kP<<<dim3(6, NH_), 256, 0, stream>>>(proto, W, P16);
    k1<<<dim3(768), 512, LDS_BYTES, stream>>>(H16, P16, chunkprod, partial);
    k2<<<dim3(NH_, B_, 4), 256, 0, stream>>>(chunkprod, partial, s0, out);
}